// Round 1
// baseline (116.658 us; speedup 1.0000x reference)
//
#include <hip/hip_runtime.h>
#include <math.h>

#define D_MODEL 512  // kernels assume D=512 (64 lanes x 8 floats)

// Pass 1: online-softmax partial accumulation.
// One wave (64 lanes) handles one chunk of RPW consecutive rows of one batch.
// Lane i owns columns [4i,4i+4) and [256+4i, 256+4i+4)  -> coalesced float4 loads.
__global__ __launch_bounds__(256) void pool_pass1(
    const float* __restrict__ x, const float* __restrict__ w,
    float* __restrict__ acc_ws, float* __restrict__ ml_ws,
    int T, int C, int RPW)
{
    const int b    = blockIdx.y;
    const int wave = threadIdx.x >> 6;
    const int lane = threadIdx.x & 63;
    const int chunk = blockIdx.x * 4 + wave;
    if (chunk >= C) return;

    const float* xb = x + (size_t)b * T * D_MODEL;

    const float4 w0 = *(const float4*)(w + 4 * lane);
    const float4 w1 = *(const float4*)(w + 256 + 4 * lane);

    float  m = -INFINITY, l = 0.0f;
    float4 a0 = make_float4(0.f, 0.f, 0.f, 0.f);
    float4 a1 = make_float4(0.f, 0.f, 0.f, 0.f);

    const float* xr = xb + (size_t)chunk * RPW * D_MODEL;
    for (int r = 0; r < RPW; ++r, xr += D_MODEL) {
        const float4 v0 = *(const float4*)(xr + 4 * lane);
        const float4 v1 = *(const float4*)(xr + 256 + 4 * lane);

        float dp = v0.x * w0.x + v0.y * w0.y + v0.z * w0.z + v0.w * w0.w
                 + v1.x * w1.x + v1.y * w1.y + v1.z * w1.z + v1.w * w1.w;
        #pragma unroll
        for (int off = 32; off >= 1; off >>= 1) dp += __shfl_xor(dp, off);
        const float s = dp;  // wave-uniform; bias dropped (softmax shift-invariant)

        if (s > m) {                       // wave-uniform branch, rare (~log RPW)
            const float scale = __expf(m - s);   // first iter: exp(-inf)=0, acc is 0 anyway
            l *= scale;
            a0.x *= scale; a0.y *= scale; a0.z *= scale; a0.w *= scale;
            a1.x *= scale; a1.y *= scale; a1.z *= scale; a1.w *= scale;
            m = s;
        }
        const float p = __expf(s - m);
        l += p;
        a0.x = fmaf(p, v0.x, a0.x);
        a0.y = fmaf(p, v0.y, a0.y);
        a0.z = fmaf(p, v0.z, a0.z);
        a0.w = fmaf(p, v0.w, a0.w);
        a1.x = fmaf(p, v1.x, a1.x);
        a1.y = fmaf(p, v1.y, a1.y);
        a1.z = fmaf(p, v1.z, a1.z);
        a1.w = fmaf(p, v1.w, a1.w);
    }

    float* accp = acc_ws + (size_t)(b * C + chunk) * D_MODEL;
    *(float4*)(accp + 4 * lane)       = a0;
    *(float4*)(accp + 256 + 4 * lane) = a1;
    if (lane == 0) {
        ml_ws[(b * C + chunk) * 2 + 0] = m;
        ml_ws[(b * C + chunk) * 2 + 1] = l;
    }
}

// Pass 2: combine chunk partials per batch.
// out[b,d] = sum_c exp(m_c - M) * acc_c[d] / (sum_c exp(m_c - M) * l_c)
__global__ __launch_bounds__(512) void pool_pass2(
    const float* __restrict__ acc_ws, const float* __restrict__ ml_ws,
    float* __restrict__ out, int C)
{
    const int b = blockIdx.x;
    const int d = threadIdx.x;

    __shared__ float s_m[256];
    __shared__ float s_l[256];
    for (int c = d; c < C; c += blockDim.x) {
        s_m[c] = ml_ws[(b * C + c) * 2 + 0];
        s_l[c] = ml_ws[(b * C + c) * 2 + 1];
    }
    __syncthreads();

    float M = -INFINITY;
    for (int c = 0; c < C; ++c) M = fmaxf(M, s_m[c]);
    float L = 0.0f;
    for (int c = 0; c < C; ++c) L += __expf(s_m[c] - M) * s_l[c];

    float sum = 0.0f;
    const float* ap = acc_ws + (size_t)b * C * D_MODEL + d;
    for (int c = 0; c < C; ++c)
        sum += __expf(s_m[c] - M) * ap[(size_t)c * D_MODEL];

    out[b * D_MODEL + d] = sum / L;
}

extern "C" void kernel_launch(void* const* d_in, const int* in_sizes, int n_in,
                              void* d_out, int out_size, void* d_ws, size_t ws_size,
                              hipStream_t stream)
{
    const float* x = (const float*)d_in[0];
    const float* w = (const float*)d_in[1];
    // d_in[2] (bias) intentionally ignored: softmax is shift-invariant.
    float* out = (float*)d_out;

    const int D = D_MODEL;
    const int B = 32;
    const int T = in_sizes[0] / (B * D);   // 8192

    // chunks per batch; shrink if workspace is small. Must divide T, multiple of 4.
    int C = 128;
    while (C > 4) {
        size_t need = (size_t)B * C * D * sizeof(float) + (size_t)B * C * 2 * sizeof(float);
        if (need <= ws_size) break;
        C >>= 1;
    }
    const int RPW = T / C;

    float* acc_ws = (float*)d_ws;
    float* ml_ws  = acc_ws + (size_t)B * C * D;

    dim3 grid1(C / 4, B);
    pool_pass1<<<grid1, 256, 0, stream>>>(x, w, acc_ws, ml_ws, T, C, RPW);
    pool_pass2<<<dim3(B), 512, 0, stream>>>(acc_ws, ml_ws, out, C);
}